// Round 9
// baseline (1182.171 us; speedup 1.0000x reference)
//
#include <hip/hip_runtime.h>
#include <cstddef>
#include <cstdint>

#define N_NODES 50000
#define N_EDGES 800000
#define F_IN 50
#define K1PAD 64
#define H_DIM 512
#define O_DIM 121
#define N_GROUPS 20
#define EPSV 1e-5f
#define M_PAD 50048   // 391 * 128
#define M_TILES 391

#define SCAN_BLK 256
#define SCAN_NBLK ((N_NODES + SCAN_BLK - 1) / SCAN_BLK)  // 196
#define WALL_EL 1769472
#define XB_EL (M_PAD * K1PAD)
#define CONV_BLKS ((XB_EL + WALL_EL) / 256)  // 19424 (exact)

typedef unsigned short u16;
typedef __attribute__((ext_vector_type(8))) short short8;          // 8 bf16 (4 VGPRs)
typedef __attribute__((ext_vector_type(8))) unsigned short u16x8;  // 16B vector
typedef __attribute__((ext_vector_type(4))) float f32x4;

__device__ __forceinline__ float b2f(u16 u) {
  union { unsigned int i; float f; } v; v.i = ((unsigned int)u) << 16; return v.f;
}
__device__ __forceinline__ u16 f2b(float f) {
  union { float f; unsigned int i; } v; v.f = f;
  unsigned int x = v.i;
  return (u16)((x + 0x7fffu + ((x >> 16) & 1u)) >> 16);  // RNE
}

__device__ __forceinline__ void gl_lds16(const void* g, void* l) {
  __builtin_amdgcn_global_load_lds(
      (__attribute__((address_space(1))) void*)(g),
      (__attribute__((address_space(3))) void*)(l), 16, 0, 0);
}

// ---------------- graph preprocessing ----------------

__global__ void k_deg(const int* __restrict__ dst, int* __restrict__ deg) {
  int e = blockIdx.x * blockDim.x + threadIdx.x;
  if (e < N_EDGES) atomicAdd(&deg[dst[e]], 1);
}

__global__ void k_scan1(const int* __restrict__ deg, int* __restrict__ off,
                        int* __restrict__ bsum) {
  __shared__ int buf[SCAN_BLK];
  int gid = blockIdx.x * SCAN_BLK + threadIdx.x;
  buf[threadIdx.x] = (gid < N_NODES) ? deg[gid] : 0;
  __syncthreads();
  for (int d = 1; d < SCAN_BLK; d <<= 1) {
    int t = (threadIdx.x >= d) ? buf[threadIdx.x - d] : 0;
    __syncthreads();
    buf[threadIdx.x] += t;
    __syncthreads();
  }
  if (gid < N_NODES) off[gid + 1] = buf[threadIdx.x];
  if (threadIdx.x == SCAN_BLK - 1) bsum[blockIdx.x] = buf[threadIdx.x];
}

__global__ void k_scan2_gbounds(int* __restrict__ bsum, const int* __restrict__ batch,
                                int* __restrict__ gstart, float* __restrict__ inv_sz) {
  int t = threadIdx.x;
  if (blockIdx.x == 0) {
    __shared__ int buf[256];
    buf[t] = (t < SCAN_NBLK) ? bsum[t] : 0;
    __syncthreads();
    for (int d = 1; d < 256; d <<= 1) {
      int v = (t >= d) ? buf[t - d] : 0;
      __syncthreads();
      buf[t] += v;
      __syncthreads();
    }
    if (t < SCAN_NBLK) bsum[t] = buf[t];
  } else {
    if (t <= N_GROUPS) {
      int lo = 0, hi = N_NODES;
      while (lo < hi) {
        int mid = (lo + hi) >> 1;
        if (batch[mid] < t) lo = mid + 1; else hi = mid;
      }
      gstart[t] = lo;
    }
    __syncthreads();
    if (t < N_GROUPS) {
      int sz = gstart[t + 1] - gstart[t];
      inv_sz[t] = 1.0f / (float)max(sz, 1);
    }
  }
}

__global__ void k_scan3prep(int* __restrict__ off, const int* __restrict__ bsum,
                            const int* __restrict__ deg, float* __restrict__ inv_deg,
                            int* __restrict__ cursor) {
  int gid = blockIdx.x * SCAN_BLK + threadIdx.x;
  if (gid < N_NODES) {
    int add = (blockIdx.x > 0) ? bsum[blockIdx.x - 1] : 0;
    int v = off[gid + 1] + add;
    off[gid + 1] = v;
    if (gid + 1 < N_NODES) cursor[gid + 1] = v;
    inv_deg[gid] = 1.0f / (float)max(deg[gid], 1);
  }
  if (gid == 0) { off[0] = 0; cursor[0] = 0; }
}

__global__ void k_scatter(const int* __restrict__ src, const int* __restrict__ dst,
                          int* __restrict__ cursor, int* __restrict__ csr_src) {
  int e = blockIdx.x * blockDim.x + threadIdx.x;
  if (e < N_EDGES) {
    int p = atomicAdd(&cursor[dst[e]], 1);
    csr_src[p] = src[e];
  }
}

// ------- conversions + layer-1 aggregation, one mixed-role dispatch ---------
struct WcSrc { const float* p[10]; };
__global__ void k_conv_agg(const float* __restrict__ x, WcSrc s,
                           u16* __restrict__ xb, u16* __restrict__ wall,
                           const int* __restrict__ off, const int* __restrict__ srcs,
                           const float* __restrict__ inv_deg, u16* __restrict__ aggx) {
  if (blockIdx.x < CONV_BLKS) {
    int idx = blockIdx.x * 256 + threadIdx.x;
    if (idx < XB_EL) {
      int r = idx >> 6, c = idx & (K1PAD - 1);
      float v = (r < N_NODES && c < F_IN) ? x[r * F_IN + c] : 0.f;
      xb[idx] = f2b(v);
      return;
    }
    idx -= XB_EL;
    const int seg_start[10] = {0, 32768, 65536, 327680, 589824, 851968,
                               1114112, 1376256, 1638400, 1703936};
    const int jr[10]  = {512, 512, 512, 512, 512, 512, 512, 512, 121, 121};
    const int kin[10] = {50, 50, 512, 512, 512, 512, 512, 512, 512, 512};
    const int ksh[10] = {6, 6, 9, 9, 9, 9, 9, 9, 9, 9};
    int sgi = 0;
#pragma unroll
    for (int t = 1; t < 10; ++t)
      if (idx >= seg_start[t]) sgi = t;
    int local = idx - seg_start[sgi];
    int j = local >> ksh[sgi];
    int k = local & ((1 << ksh[sgi]) - 1);
    float v = (j < jr[sgi] && k < kin[sgi]) ? s.p[sgi][j * kin[sgi] + k] : 0.f;
    wall[idx] = f2b(v);
  } else {
    // layer-1 agg: gather f32 x rows (independent of the convert role)
    int aid = blockIdx.x - CONV_BLKS;
    int n = aid * 4 + (threadIdx.x >> 6);
    if (n >= N_NODES) return;
    int f = threadIdx.x & 63;
    int b = off[n], e = off[n + 1];
    float sacc = 0.f;
    if (f < F_IN)
      for (int i = b; i < e; ++i) sacc += x[(size_t)srcs[i] * F_IN + f];
    aggx[(size_t)n * K1PAD + f] = f2b(sacc * inv_deg[n]);
  }
}

// ---------------- aggregation (layers 2..4) ----------------
// pinned at the L2-miss/L3 path ceiling (~111us); nt stores to avoid
// polluting caches with the streaming output.
__global__ __launch_bounds__(512) void k_agg512(
    const u16* __restrict__ h, const int* __restrict__ off,
    const int* __restrict__ srcs, const float* __restrict__ inv_deg,
    u16* __restrict__ agg) {
  __shared__ float part[4][64][8];  // 8 KB
  int slot = threadIdx.y >> 1;
  int sub = threadIdx.y & 1;
  int n = blockIdx.x * 4 + slot;
  int t = threadIdx.x;
  float a[8] = {0.f, 0.f, 0.f, 0.f, 0.f, 0.f, 0.f, 0.f};
  if (n < N_NODES) {
    int b = off[n], e = off[n + 1];
    int half = (e - b + 1) >> 1;
    int lo = b + sub * half;
    int hi = min(lo + half, e);
    int i = lo;
    for (; i + 4 <= hi; i += 4) {
      u16x8 v0 = ((const u16x8*)(h + (size_t)srcs[i + 0] * H_DIM))[t];
      u16x8 v1 = ((const u16x8*)(h + (size_t)srcs[i + 1] * H_DIM))[t];
      u16x8 v2 = ((const u16x8*)(h + (size_t)srcs[i + 2] * H_DIM))[t];
      u16x8 v3 = ((const u16x8*)(h + (size_t)srcs[i + 3] * H_DIM))[t];
#pragma unroll
      for (int j = 0; j < 8; ++j)
        a[j] += (b2f(v0[j]) + b2f(v1[j])) + (b2f(v2[j]) + b2f(v3[j]));
    }
    for (; i < hi; ++i) {
      u16x8 v0 = ((const u16x8*)(h + (size_t)srcs[i] * H_DIM))[t];
#pragma unroll
      for (int j = 0; j < 8; ++j) a[j] += b2f(v0[j]);
    }
  }
  if (sub == 1) {
#pragma unroll
    for (int j = 0; j < 8; ++j) part[slot][t][j] = a[j];
  }
  __syncthreads();
  if (sub == 0 && n < N_NODES) {
    float w = inv_deg[n];
    u16x8 r;
#pragma unroll
    for (int j = 0; j < 8; ++j) r[j] = f2b((a[j] + part[slot][t][j]) * w);
    __builtin_nontemporal_store(r, (u16x8*)(agg + (size_t)n * H_DIM) + t);
  }
}

// layer 5 final: out[n] = inv_deg[n]*sum(Pl[src]) + Pr[n] + bias (121 cols)
__global__ __launch_bounds__(256) void k_agg_final(
    const u16* __restrict__ Plb, const float* __restrict__ Prf,
    const int* __restrict__ off, const int* __restrict__ srcs,
    const float* __restrict__ inv_deg, const float* __restrict__ bias,
    float* __restrict__ out) {
  int n = blockIdx.x * 8 + (threadIdx.x >> 5);
  if (n >= N_NODES) return;
  int l = threadIdx.x & 31;
  int c0 = l * 4;
  int b = off[n], e = off[n + 1];
  float a0 = 0.f, a1 = 0.f, a2 = 0.f, a3 = 0.f;
  int i = b;
  for (; i + 2 <= e; i += 2) {
    ushort4 v0 = ((const ushort4*)(Plb + (size_t)srcs[i] * 128))[l];
    ushort4 v1 = ((const ushort4*)(Plb + (size_t)srcs[i + 1] * 128))[l];
    a0 += b2f(v0.x) + b2f(v1.x); a1 += b2f(v0.y) + b2f(v1.y);
    a2 += b2f(v0.z) + b2f(v1.z); a3 += b2f(v0.w) + b2f(v1.w);
  }
  if (i < e) {
    ushort4 v0 = ((const ushort4*)(Plb + (size_t)srcs[i] * 128))[l];
    a0 += b2f(v0.x); a1 += b2f(v0.y); a2 += b2f(v0.z); a3 += b2f(v0.w);
  }
  float w = inv_deg[n];
  float4 pr = ((const float4*)(Prf + (size_t)n * 128))[l];
  float r0 = a0 * w + pr.x, r1 = a1 * w + pr.y;
  float r2 = a2 * w + pr.z, r3 = a3 * w + pr.w;
  size_t ob = (size_t)n * O_DIM;
  if (c0 + 0 < O_DIM) out[ob + c0 + 0] = r0 + bias[c0 + 0];
  if (c0 + 1 < O_DIM) out[ob + c0 + 1] = r1 + bias[c0 + 1];
  if (c0 + 2 < O_DIM) out[ob + c0 + 2] = r2 + bias[c0 + 2];
  if (c0 + 3 < O_DIM) out[ob + c0 + 3] = r3 + bias[c0 + 3];
}

// ---------------- MFMA GEMM ----------------
// DUAL(OUTMODE 0): C = A*Wl^T + X*Wr^T + b, stats fused in epilogue.
// !DUAL(OUTMODE 1): P = A*Wl^T; cols<128 -> bf16 C0, cols>=128 -> f32 C1.
// NORM: A staged via register path with relu(x*S+T) (norm folded into the
//   GEMM's A-read; eliminates the standalone apply for layer 4 -> 5).

#define TM 128
#define TK 32

template <int JB, bool DUAL, int OUTMODE, bool NORM>
__global__ __launch_bounds__(256, 4) void k_gemm_mfma(
    const u16* __restrict__ A, const u16* __restrict__ X,
    const u16* __restrict__ Wl, const u16* __restrict__ Wr,
    const float* __restrict__ bias, void* __restrict__ C0,
    void* __restrict__ C1, const int* __restrict__ batch,
    float* __restrict__ ssum, float* __restrict__ ssq,
    const float* __restrict__ Sn, const float* __restrict__ Tn, int K) {
  __shared__ u16 As[TM * TK];
  __shared__ u16 Ls[TM * TK];
  __shared__ u16 Xs[DUAL ? TM * TK : 1];
  __shared__ u16 Rs[DUAL ? TM * TK : 1];

  int id = blockIdx.x;
  const int nfull = (M_TILES >> 3) * 8 * JB;
  int m_t, j_t;
  if (id < nfull) {
    m_t = (id / (8 * JB)) * 8 + (id & 7);
    j_t = (id >> 3) & (JB - 1);
  } else {
    int rem = id - nfull;
    const int nrem = M_TILES & 7;  // 7
    m_t = (M_TILES & ~7) + rem % nrem;
    j_t = rem / nrem;
  }
  int m0 = m_t * TM;
  int j0 = j_t * 128;

  int tid = threadIdx.x;
  int lane = tid & 63;
  int wave = tid >> 6;
  int quad = lane >> 4;
  int lr = lane & 15;
  int wm = (wave & 1) * 64;
  int wn = (wave >> 1) * 64;

  f32x4 acc[4][4] = {};

  int sr = tid >> 2;
  int sc = (tid & 3) * 8;
  size_t moff0 = (size_t)(m0 + sr) * K + sc;
  size_t moff1 = moff0 + (size_t)64 * K;
  size_t joff0 = (size_t)(j0 + sr) * K + sc;
  size_t joff1 = joff0 + (size_t)64 * K;
  const int dofs = tid * 8;

  int g0 = 0, g1 = 0;
  if constexpr (NORM) {
    int r0 = m0 + sr, r1 = m0 + sr + 64;
    g0 = (r0 < N_NODES) ? batch[r0] : 0;
    g1 = (r1 < N_NODES) ? batch[r1] : 0;
  }

  for (int k0 = 0; k0 < K; k0 += TK) {
    __syncthreads();
    if constexpr (!NORM) {
      gl_lds16(A + moff0 + k0, As + dofs);
      gl_lds16(A + moff1 + k0, As + 2048 + dofs);
    } else {
      // register-path A staging with inline norm+relu (norm over feature
      // cols == K dim here), then bf16 round + LDS write (same layout as
      // the wave-uniform global_load_lds destination).
      u16x8 ra = *(const u16x8*)(A + moff0 + k0);
      u16x8 rb = *(const u16x8*)(A + moff1 + k0);
      f32x4 s0a = *(const f32x4*)(Sn + g0 * H_DIM + k0 + sc);
      f32x4 s0b = *(const f32x4*)(Sn + g0 * H_DIM + k0 + sc + 4);
      f32x4 t0a = *(const f32x4*)(Tn + g0 * H_DIM + k0 + sc);
      f32x4 t0b = *(const f32x4*)(Tn + g0 * H_DIM + k0 + sc + 4);
      f32x4 s1a = *(const f32x4*)(Sn + g1 * H_DIM + k0 + sc);
      f32x4 s1b = *(const f32x4*)(Sn + g1 * H_DIM + k0 + sc + 4);
      f32x4 t1a = *(const f32x4*)(Tn + g1 * H_DIM + k0 + sc);
      f32x4 t1b = *(const f32x4*)(Tn + g1 * H_DIM + k0 + sc + 4);
      u16x8 wa, wb;
#pragma unroll
      for (int j = 0; j < 4; ++j) {
        wa[j]     = f2b(fmaxf(b2f(ra[j])     * s0a[j] + t0a[j], 0.f));
        wa[j + 4] = f2b(fmaxf(b2f(ra[j + 4]) * s0b[j] + t0b[j], 0.f));
        wb[j]     = f2b(fmaxf(b2f(rb[j])     * s1a[j] + t1a[j], 0.f));
        wb[j + 4] = f2b(fmaxf(b2f(rb[j + 4]) * s1b[j] + t1b[j], 0.f));
      }
      *(u16x8*)(As + dofs) = wa;
      *(u16x8*)(As + 2048 + dofs) = wb;
    }
    gl_lds16(Wl + joff0 + k0, Ls + dofs);
    gl_lds16(Wl + joff1 + k0, Ls + 2048 + dofs);
    if constexpr (DUAL) {
      gl_lds16(X + moff0 + k0, Xs + dofs);
      gl_lds16(X + moff1 + k0, Xs + 2048 + dofs);
      gl_lds16(Wr + joff0 + k0, Rs + dofs);
      gl_lds16(Wr + joff1 + k0, Rs + 2048 + dofs);
    }
    __syncthreads();
    {
      short8 af[4], lf[4];
#pragma unroll
      for (int t = 0; t < 4; ++t) {
        af[t] = *(const short8*)(As + (wm + t * 16 + lr) * TK + quad * 8);
        lf[t] = *(const short8*)(Ls + (wn + t * 16 + lr) * TK + quad * 8);
      }
#pragma unroll
      for (int ti = 0; ti < 4; ++ti)
#pragma unroll
        for (int tj = 0; tj < 4; ++tj)
          acc[ti][tj] = __builtin_amdgcn_mfma_f32_16x16x32_bf16(
              af[ti], lf[tj], acc[ti][tj], 0, 0, 0);
    }
    if constexpr (DUAL) {
      short8 xf[4], rf[4];
#pragma unroll
      for (int t = 0; t < 4; ++t) {
        xf[t] = *(const short8*)(Xs + (wm + t * 16 + lr) * TK + quad * 8);
        rf[t] = *(const short8*)(Rs + (wn + t * 16 + lr) * TK + quad * 8);
      }
#pragma unroll
      for (int ti = 0; ti < 4; ++ti)
#pragma unroll
        for (int tj = 0; tj < 4; ++tj)
          acc[ti][tj] = __builtin_amdgcn_mfma_f32_16x16x32_bf16(
              xf[ti], rf[tj], acc[ti][tj], 0, 0, 0);
    }
  }

  // epilogue: C/D layout col=lane&15, row=quad*4+reg (m89-verified)
  if constexpr (OUTMODE == 0) {
    int glo = batch[m0];
    int lastrow = m0 + TM - 1;
    bool fast = (lastrow < N_NODES) && (batch[lastrow] == glo);
#pragma unroll
    for (int tj = 0; tj < 4; ++tj) {
      int gcol = j0 + wn + tj * 16 + lr;
      float bv = bias[gcol];
      float s = 0.f, q = 0.f;
#pragma unroll
      for (int ti = 0; ti < 4; ++ti) {
        f32x4 v = acc[ti][tj];
        int rbase = m0 + wm + ti * 16 + quad * 4;
        if (fast) {
#pragma unroll
          for (int r = 0; r < 4; ++r) {
            float val = v[r] + bv;
            ((u16*)C0)[(size_t)(rbase + r) * H_DIM + gcol] = f2b(val);
            s += val; q += val * val;
          }
        } else {
          if (rbase + 3 < N_NODES && batch[rbase] == batch[rbase + 3]) {
            float s4 = 0.f, q4 = 0.f;
#pragma unroll
            for (int r = 0; r < 4; ++r) {
              float val = v[r] + bv;
              ((u16*)C0)[(size_t)(rbase + r) * H_DIM + gcol] = f2b(val);
              s4 += val; q4 += val * val;
            }
            int g = batch[rbase];
            atomicAdd(&ssum[g * H_DIM + gcol], s4);
            atomicAdd(&ssq[g * H_DIM + gcol], q4);
          } else {
#pragma unroll
            for (int r = 0; r < 4; ++r) {
              int grow = rbase + r;
              if (grow < N_NODES) {
                float val = v[r] + bv;
                ((u16*)C0)[(size_t)grow * H_DIM + gcol] = f2b(val);
                int g = batch[grow];
                atomicAdd(&ssum[g * H_DIM + gcol], val);
                atomicAdd(&ssq[g * H_DIM + gcol], val * val);
              }
            }
          }
        }
      }
      if (fast) {
        s += __shfl_xor(s, 16); s += __shfl_xor(s, 32);
        q += __shfl_xor(q, 16); q += __shfl_xor(q, 32);
        if (quad == 0) {
          atomicAdd(&ssum[glo * H_DIM + gcol], s);
          atomicAdd(&ssq[glo * H_DIM + gcol], q);
        }
      }
    }
  } else {
#pragma unroll
    for (int tj = 0; tj < 4; ++tj) {
      int gcol = j0 + wn + tj * 16 + lr;
#pragma unroll
      for (int ti = 0; ti < 4; ++ti) {
        f32x4 v = acc[ti][tj];
#pragma unroll
        for (int r = 0; r < 4; ++r) {
          int grow = m0 + wm + ti * 16 + quad * 4 + r;
          if (gcol < 128)
            ((u16*)C0)[(size_t)grow * 128 + gcol] = f2b(v[r]);
          else
            ((float*)C1)[(size_t)grow * 128 + (gcol - 128)] = v[r];
        }
      }
    }
  }
}

// ------------- GraphNorm apply (precomp folded in, raw -> normed) -----------

__global__ void k_apply(const u16* __restrict__ hr, u16* __restrict__ hn,
                        const int* __restrict__ batch,
                        const float* __restrict__ ssum, const float* __restrict__ ssq,
                        const float* __restrict__ inv_sz, const float* __restrict__ gw,
                        const float* __restrict__ gb, const float* __restrict__ alpha) {
  int tid = blockIdx.x * blockDim.x + threadIdx.x;
  int n = tid >> 5;            // 32 threads per row, 16 cols each
  if (n >= N_NODES) return;
  int c0 = (tid & 31) << 4;
  int g = batch[n];
  float is = inv_sz[g];
  u16x8 h0v = *(const u16x8*)(hr + (size_t)n * H_DIM + c0);
  u16x8 h1v = *(const u16x8*)(hr + (size_t)n * H_DIM + c0 + 8);
  u16x8 o0, o1;
#pragma unroll
  for (int j = 0; j < 16; ++j) {
    int c = c0 + j;
    float m = ssum[g * H_DIM + c] * is;
    float a = alpha[c];
    float var = fmaxf(ssq[g * H_DIM + c] * is - a * (2.f - a) * m * m, 0.f);
    float sc = rsqrtf(var + EPSV) * gw[c];
    float xv = (j < 8) ? b2f(h0v[j]) : b2f(h1v[j - 8]);
    float y = fmaxf((xv - a * m) * sc + gb[c], 0.f);
    if (j < 8) o0[j] = f2b(y); else o1[j - 8] = f2b(y);
  }
  __builtin_nontemporal_store(o0, (u16x8*)(hn + (size_t)n * H_DIM + c0));
  __builtin_nontemporal_store(o1, (u16x8*)(hn + (size_t)n * H_DIM + c0 + 8));
}

// precomp for the L5 NORM-staging GEMM (stats of layer 4)
__global__ void k_precomp(const float* __restrict__ ssum, const float* __restrict__ ssq,
                          const float* __restrict__ inv_sz, const float* __restrict__ gw,
                          const float* __restrict__ gb, const float* __restrict__ alpha,
                          float* __restrict__ S, float* __restrict__ T) {
  int idx = blockIdx.x * blockDim.x + threadIdx.x;
  if (idx >= N_GROUPS * H_DIM) return;
  int g = idx >> 9;
  int c = idx & (H_DIM - 1);
  float is = inv_sz[g];
  float m = ssum[idx] * is;
  float a = alpha[c];
  float var = fmaxf(ssq[idx] * is - a * (2.f - a) * m * m, 0.f);
  float inv = rsqrtf(var + EPSV);
  float sc = inv * gw[c];
  S[idx] = sc;
  T[idx] = gb[c] - a * m * sc;
}

// ---------------- driver ----------------

extern "C" void kernel_launch(void* const* d_in, const int* in_sizes, int n_in,
                              void* d_out, int out_size, void* d_ws, size_t ws_size,
                              hipStream_t stream) {
  const float* x = (const float*)d_in[0];
  const int* edge = (const int*)d_in[1];
  const int* batch = (const int*)d_in[2];
  const float *Wl[5], *Wr[5], *bb[5];
  for (int i = 0; i < 5; ++i) {
    Wl[i] = (const float*)d_in[3 + 3 * i];
    Wr[i] = (const float*)d_in[4 + 3 * i];
    bb[i] = (const float*)d_in[5 + 3 * i];
  }
  const float *gamma[4], *beta[4], *alpha[4];
  for (int i = 0; i < 4; ++i) {
    gamma[i] = (const float*)d_in[18 + 3 * i];
    beta[i]  = (const float*)d_in[19 + 3 * i];
    alpha[i] = (const float*)d_in[20 + 3 * i];
  }
  const int* srcv = edge;
  const int* dstv = edge + N_EDGES;

  char* base = (char*)d_ws;
  size_t off = 0;
  auto carve = [&](size_t bytes) -> char* {
    char* p = base + off;
    off = (off + bytes + 255) & ~(size_t)255;
    return p;
  };
  int* deg       = (int*)carve((size_t)N_NODES * 4);
  float* inv_deg = (float*)carve((size_t)N_NODES * 4);
  int* csr_off   = (int*)carve((size_t)(N_NODES + 1) * 4);
  int* cursor    = (int*)carve((size_t)N_NODES * 4);
  int* csr_src   = (int*)carve((size_t)N_EDGES * 4);
  int* bsum      = (int*)carve((size_t)SCAN_NBLK * 4);
  int* gstart    = (int*)carve((size_t)(N_GROUPS + 1) * 4);
  float* inv_sz  = (float*)carve((size_t)N_GROUPS * 4);
  float* stats   = (float*)carve((size_t)4 * 2 * N_GROUPS * H_DIM * 4);
  float* Sbuf    = (float*)carve((size_t)N_GROUPS * H_DIM * 4);
  float* Tbuf    = (float*)carve((size_t)N_GROUPS * H_DIM * 4);
  u16* xb        = (u16*)carve((size_t)XB_EL * 2);
  u16* aggx      = (u16*)carve((size_t)XB_EL * 2);
  u16* h0        = (u16*)carve((size_t)M_PAD * H_DIM * 2);  // raw GEMM out
  u16* h1        = (u16*)carve((size_t)M_PAD * H_DIM * 2);  // normed
  u16* h2        = (u16*)carve((size_t)M_PAD * H_DIM * 2);  // agg
  u16* wall      = (u16*)carve((size_t)WALL_EL * 2);
  (void)ws_size; (void)in_sizes; (void)n_in; (void)out_size;

  u16* w1lb = wall;
  u16* w1rb = wall + 32768;
  u16* w2lb = wall + 65536;
  u16* w2rb = wall + 327680;
  u16* w3lb = wall + 589824;
  u16* w3rb = wall + 851968;
  u16* w4lb = wall + 1114112;
  u16* w4rb = wall + 1376256;
  u16* w5cat = wall + 1638400;  // 256 x 512

  // L5 P buffers alias h1 (dead after GEMM4)
  u16* Plb = h1;
  float* Prf = (float*)((char*)h1 + (size_t)M_PAD * 128 * 2);

  // graph preprocessing
  hipMemsetAsync(deg, 0, (size_t)N_NODES * 4, stream);
  k_deg<<<(N_EDGES + 255) / 256, 256, 0, stream>>>(dstv, deg);
  k_scan1<<<SCAN_NBLK, SCAN_BLK, 0, stream>>>(deg, csr_off, bsum);
  k_scan2_gbounds<<<2, 256, 0, stream>>>(bsum, batch, gstart, inv_sz);
  k_scan3prep<<<SCAN_NBLK, SCAN_BLK, 0, stream>>>(csr_off, bsum, deg, inv_deg, cursor);
  k_scatter<<<(N_EDGES + 255) / 256, 256, 0, stream>>>(srcv, dstv, cursor, csr_src);
  hipMemsetAsync(stats, 0, (size_t)4 * 2 * N_GROUPS * H_DIM * 4, stream);

  WcSrc ws_src;
  ws_src.p[0] = Wl[0]; ws_src.p[1] = Wr[0];
  ws_src.p[2] = Wl[1]; ws_src.p[3] = Wr[1];
  ws_src.p[4] = Wl[2]; ws_src.p[5] = Wr[2];
  ws_src.p[6] = Wl[3]; ws_src.p[7] = Wr[3];
  ws_src.p[8] = Wl[4]; ws_src.p[9] = Wr[4];
  // convert (x->xb, W->wall) + layer-1 gather, one mixed dispatch
  k_conv_agg<<<CONV_BLKS + (N_NODES + 3) / 4, 256, 0, stream>>>(
      x, ws_src, xb, wall, csr_off, csr_src, inv_deg, aggx);

  const int nblk_main = M_TILES * 4;  // JB=4
  const int nblk_l5   = M_TILES * 2;  // JB=2
  dim3 aggblk(64, 8);
  int aggrid = (N_NODES + 3) / 4;
  int apgrid = (N_NODES * 32 + 255) / 256;  // 6250

  auto stat_ptr = [&](int l) { return stats + (size_t)l * 2 * N_GROUPS * H_DIM; };
  auto apply = [&](int l) {
    k_apply<<<apgrid, 256, 0, stream>>>(
        h0, h1, batch, stat_ptr(l), stat_ptr(l) + N_GROUPS * H_DIM,
        inv_sz, gamma[l], beta[l], alpha[l]);
  };

  // layer 1 (K = 64 padded)
  k_gemm_mfma<4, true, 0, false><<<nblk_main, 256, 0, stream>>>(
      aggx, xb, w1lb, w1rb, bb[0], h0, nullptr, batch,
      stat_ptr(0), stat_ptr(0) + N_GROUPS * H_DIM, nullptr, nullptr, K1PAD);
  apply(0);

  // layers 2..4
  const u16* wls[3] = {w2lb, w3lb, w4lb};
  const u16* wrs[3] = {w2rb, w3rb, w4rb};
  for (int l = 1; l <= 3; ++l) {
    k_agg512<<<aggrid, aggblk, 0, stream>>>(h1, csr_off, csr_src, inv_deg, h2);
    k_gemm_mfma<4, true, 0, false><<<nblk_main, 256, 0, stream>>>(
        h2, h1, wls[l - 1], wrs[l - 1], bb[l], h0, nullptr, batch,
        stat_ptr(l), stat_ptr(l) + N_GROUPS * H_DIM, nullptr, nullptr, H_DIM);
    if (l < 3) apply(l);
  }

  // layer 4 norm folded into the L5 GEMM's A-staging (no standalone apply):
  k_precomp<<<(N_GROUPS * H_DIM + 255) / 256, 256, 0, stream>>>(
      stat_ptr(3), stat_ptr(3) + N_GROUPS * H_DIM, inv_sz,
      gamma[3], beta[3], alpha[3], Sbuf, Tbuf);
  // layer 5 via linearity: P = relu(norm(h0)) @ [W5l|W5r]^T (J=256)
  k_gemm_mfma<2, false, 1, true><<<nblk_l5, 256, 0, stream>>>(
      h0, nullptr, w5cat, nullptr, nullptr, Plb, Prf, batch,
      nullptr, nullptr, Sbuf, Tbuf, H_DIM);
  k_agg_final<<<(N_NODES + 7) / 8, 256, 0, stream>>>(
      Plb, Prf, csr_off, csr_src, inv_deg, bb[4], (float*)d_out);
}

// Round 10
// 1092.074 us; speedup vs baseline: 1.0825x; 1.0825x over previous
//
#include <hip/hip_runtime.h>
#include <cstddef>
#include <cstdint>

#define N_NODES 50000
#define N_EDGES 800000
#define F_IN 50
#define K1PAD 64
#define H_DIM 512
#define O_DIM 121
#define N_GROUPS 20
#define EPSV 1e-5f
#define M_PAD 50048   // 391 * 128
#define M_TILES 391

#define SCAN_BLK 256
#define SCAN_NBLK ((N_NODES + SCAN_BLK - 1) / SCAN_BLK)  // 196
#define WALL_EL 1769472
#define XB_EL (M_PAD * K1PAD)
#define CONV_BLKS ((XB_EL + WALL_EL) / 256)  // 19424 (exact)

typedef unsigned short u16;
typedef __attribute__((ext_vector_type(8))) short short8;          // 8 bf16 (4 VGPRs)
typedef __attribute__((ext_vector_type(8))) unsigned short u16x8;  // 16B vector
typedef __attribute__((ext_vector_type(4))) float f32x4;

__device__ __forceinline__ float b2f(u16 u) {
  union { unsigned int i; float f; } v; v.i = ((unsigned int)u) << 16; return v.f;
}
__device__ __forceinline__ u16 f2b(float f) {
  union { float f; unsigned int i; } v; v.f = f;
  unsigned int x = v.i;
  return (u16)((x + 0x7fffu + ((x >> 16) & 1u)) >> 16);  // RNE
}

__device__ __forceinline__ void gl_lds16(const void* g, void* l) {
  __builtin_amdgcn_global_load_lds(
      (__attribute__((address_space(1))) void*)(g),
      (__attribute__((address_space(3))) void*)(l), 16, 0, 0);
}

// ---------------- graph preprocessing ----------------

__global__ void k_deg(const int* __restrict__ dst, int* __restrict__ deg) {
  int e = blockIdx.x * blockDim.x + threadIdx.x;
  if (e < N_EDGES) atomicAdd(&deg[dst[e]], 1);
}

__global__ void k_scan1(const int* __restrict__ deg, int* __restrict__ off,
                        int* __restrict__ bsum) {
  __shared__ int buf[SCAN_BLK];
  int gid = blockIdx.x * SCAN_BLK + threadIdx.x;
  buf[threadIdx.x] = (gid < N_NODES) ? deg[gid] : 0;
  __syncthreads();
  for (int d = 1; d < SCAN_BLK; d <<= 1) {
    int t = (threadIdx.x >= d) ? buf[threadIdx.x - d] : 0;
    __syncthreads();
    buf[threadIdx.x] += t;
    __syncthreads();
  }
  if (gid < N_NODES) off[gid + 1] = buf[threadIdx.x];
  if (threadIdx.x == SCAN_BLK - 1) bsum[blockIdx.x] = buf[threadIdx.x];
}

__global__ void k_scan2_gbounds(int* __restrict__ bsum, const int* __restrict__ batch,
                                int* __restrict__ gstart, float* __restrict__ inv_sz) {
  int t = threadIdx.x;
  if (blockIdx.x == 0) {
    __shared__ int buf[256];
    buf[t] = (t < SCAN_NBLK) ? bsum[t] : 0;
    __syncthreads();
    for (int d = 1; d < 256; d <<= 1) {
      int v = (t >= d) ? buf[t - d] : 0;
      __syncthreads();
      buf[t] += v;
      __syncthreads();
    }
    if (t < SCAN_NBLK) bsum[t] = buf[t];
  } else {
    if (t <= N_GROUPS) {
      int lo = 0, hi = N_NODES;
      while (lo < hi) {
        int mid = (lo + hi) >> 1;
        if (batch[mid] < t) lo = mid + 1; else hi = mid;
      }
      gstart[t] = lo;
    }
    __syncthreads();
    if (t < N_GROUPS) {
      int sz = gstart[t + 1] - gstart[t];
      inv_sz[t] = 1.0f / (float)max(sz, 1);
    }
  }
}

__global__ void k_scan3prep(int* __restrict__ off, const int* __restrict__ bsum,
                            const int* __restrict__ deg, float* __restrict__ inv_deg,
                            int* __restrict__ cursor) {
  int gid = blockIdx.x * SCAN_BLK + threadIdx.x;
  if (gid < N_NODES) {
    int add = (blockIdx.x > 0) ? bsum[blockIdx.x - 1] : 0;
    int v = off[gid + 1] + add;
    off[gid + 1] = v;
    if (gid + 1 < N_NODES) cursor[gid + 1] = v;
    inv_deg[gid] = 1.0f / (float)max(deg[gid], 1);
  }
  if (gid == 0) { off[0] = 0; cursor[0] = 0; }
}

__global__ void k_scatter(const int* __restrict__ src, const int* __restrict__ dst,
                          int* __restrict__ cursor, int* __restrict__ csr_src) {
  int e = blockIdx.x * blockDim.x + threadIdx.x;
  if (e < N_EDGES) {
    int p = atomicAdd(&cursor[dst[e]], 1);
    csr_src[p] = src[e];
  }
}

// ------- conversions + layer-1 aggregation, one mixed-role dispatch ---------
struct WcSrc { const float* p[10]; };
__global__ void k_conv_agg(const float* __restrict__ x, WcSrc s,
                           u16* __restrict__ xb, u16* __restrict__ wall,
                           const int* __restrict__ off, const int* __restrict__ srcs,
                           const float* __restrict__ inv_deg, u16* __restrict__ aggx) {
  if (blockIdx.x < CONV_BLKS) {
    int idx = blockIdx.x * 256 + threadIdx.x;
    if (idx < XB_EL) {
      int r = idx >> 6, c = idx & (K1PAD - 1);
      float v = (r < N_NODES && c < F_IN) ? x[r * F_IN + c] : 0.f;
      xb[idx] = f2b(v);
      return;
    }
    idx -= XB_EL;
    const int seg_start[10] = {0, 32768, 65536, 327680, 589824, 851968,
                               1114112, 1376256, 1638400, 1703936};
    const int jr[10]  = {512, 512, 512, 512, 512, 512, 512, 512, 121, 121};
    const int kin[10] = {50, 50, 512, 512, 512, 512, 512, 512, 512, 512};
    const int ksh[10] = {6, 6, 9, 9, 9, 9, 9, 9, 9, 9};
    int sgi = 0;
#pragma unroll
    for (int t = 1; t < 10; ++t)
      if (idx >= seg_start[t]) sgi = t;
    int local = idx - seg_start[sgi];
    int j = local >> ksh[sgi];
    int k = local & ((1 << ksh[sgi]) - 1);
    float v = (j < jr[sgi] && k < kin[sgi]) ? s.p[sgi][j * kin[sgi] + k] : 0.f;
    wall[idx] = f2b(v);
  } else {
    // layer-1 agg: gather f32 x rows (independent of the convert role)
    int aid = blockIdx.x - CONV_BLKS;
    int n = aid * 4 + (threadIdx.x >> 6);
    if (n >= N_NODES) return;
    int f = threadIdx.x & 63;
    int b = off[n], e = off[n + 1];
    float sacc = 0.f;
    if (f < F_IN)
      for (int i = b; i < e; ++i) sacc += x[(size_t)srcs[i] * F_IN + f];
    aggx[(size_t)n * K1PAD + f] = f2b(sacc * inv_deg[n]);
  }
}

// ---------------- aggregation (layers 2..4) ----------------
// pinned at the L2-miss/L3 path ceiling (~111us). REGULAR stores: round 9's
// nontemporal variant evicted h from L2 and pushed the downstream GEMM's
// A/X reads onto the L3-latency path (GEMM 95->113us) — reverted.
__global__ __launch_bounds__(512) void k_agg512(
    const u16* __restrict__ h, const int* __restrict__ off,
    const int* __restrict__ srcs, const float* __restrict__ inv_deg,
    u16* __restrict__ agg) {
  __shared__ float part[4][64][8];  // 8 KB
  int slot = threadIdx.y >> 1;
  int sub = threadIdx.y & 1;
  int n = blockIdx.x * 4 + slot;
  int t = threadIdx.x;
  float a[8] = {0.f, 0.f, 0.f, 0.f, 0.f, 0.f, 0.f, 0.f};
  if (n < N_NODES) {
    int b = off[n], e = off[n + 1];
    int half = (e - b + 1) >> 1;
    int lo = b + sub * half;
    int hi = min(lo + half, e);
    int i = lo;
    for (; i + 4 <= hi; i += 4) {
      u16x8 v0 = ((const u16x8*)(h + (size_t)srcs[i + 0] * H_DIM))[t];
      u16x8 v1 = ((const u16x8*)(h + (size_t)srcs[i + 1] * H_DIM))[t];
      u16x8 v2 = ((const u16x8*)(h + (size_t)srcs[i + 2] * H_DIM))[t];
      u16x8 v3 = ((const u16x8*)(h + (size_t)srcs[i + 3] * H_DIM))[t];
#pragma unroll
      for (int j = 0; j < 8; ++j)
        a[j] += (b2f(v0[j]) + b2f(v1[j])) + (b2f(v2[j]) + b2f(v3[j]));
    }
    for (; i < hi; ++i) {
      u16x8 v0 = ((const u16x8*)(h + (size_t)srcs[i] * H_DIM))[t];
#pragma unroll
      for (int j = 0; j < 8; ++j) a[j] += b2f(v0[j]);
    }
  }
  if (sub == 1) {
#pragma unroll
    for (int j = 0; j < 8; ++j) part[slot][t][j] = a[j];
  }
  __syncthreads();
  if (sub == 0 && n < N_NODES) {
    float w = inv_deg[n];
    u16x8 r;
#pragma unroll
    for (int j = 0; j < 8; ++j) r[j] = f2b((a[j] + part[slot][t][j]) * w);
    ((u16x8*)(agg + (size_t)n * H_DIM))[t] = r;
  }
}

// layer 5 final: out[n] = inv_deg[n]*sum(Pl[src]) + Pr[n] + bias (121 cols)
__global__ __launch_bounds__(256) void k_agg_final(
    const u16* __restrict__ Plb, const float* __restrict__ Prf,
    const int* __restrict__ off, const int* __restrict__ srcs,
    const float* __restrict__ inv_deg, const float* __restrict__ bias,
    float* __restrict__ out) {
  int n = blockIdx.x * 8 + (threadIdx.x >> 5);
  if (n >= N_NODES) return;
  int l = threadIdx.x & 31;
  int c0 = l * 4;
  int b = off[n], e = off[n + 1];
  float a0 = 0.f, a1 = 0.f, a2 = 0.f, a3 = 0.f;
  int i = b;
  for (; i + 2 <= e; i += 2) {
    ushort4 v0 = ((const ushort4*)(Plb + (size_t)srcs[i] * 128))[l];
    ushort4 v1 = ((const ushort4*)(Plb + (size_t)srcs[i + 1] * 128))[l];
    a0 += b2f(v0.x) + b2f(v1.x); a1 += b2f(v0.y) + b2f(v1.y);
    a2 += b2f(v0.z) + b2f(v1.z); a3 += b2f(v0.w) + b2f(v1.w);
  }
  if (i < e) {
    ushort4 v0 = ((const ushort4*)(Plb + (size_t)srcs[i] * 128))[l];
    a0 += b2f(v0.x); a1 += b2f(v0.y); a2 += b2f(v0.z); a3 += b2f(v0.w);
  }
  float w = inv_deg[n];
  float4 pr = ((const float4*)(Prf + (size_t)n * 128))[l];
  float r0 = a0 * w + pr.x, r1 = a1 * w + pr.y;
  float r2 = a2 * w + pr.z, r3 = a3 * w + pr.w;
  size_t ob = (size_t)n * O_DIM;
  if (c0 + 0 < O_DIM) out[ob + c0 + 0] = r0 + bias[c0 + 0];
  if (c0 + 1 < O_DIM) out[ob + c0 + 1] = r1 + bias[c0 + 1];
  if (c0 + 2 < O_DIM) out[ob + c0 + 2] = r2 + bias[c0 + 2];
  if (c0 + 3 < O_DIM) out[ob + c0 + 3] = r3 + bias[c0 + 3];
}

// ---------------- MFMA GEMM ----------------
// DUAL(OUTMODE 0): C = A*Wl^T + X*Wr^T + b, stats fused in epilogue.
// !DUAL(OUTMODE 1): P = A*Wl^T; cols<128 -> bf16 C0, cols>=128 -> f32 C1.
// (round-9's NORM register-path A staging reverted: it serialized loads+VALU
//  into the pre-barrier path and regressed the L5 GEMM.)

#define TM 128
#define TK 32

template <int JB, bool DUAL, int OUTMODE>
__global__ __launch_bounds__(256, 4) void k_gemm_mfma(
    const u16* __restrict__ A, const u16* __restrict__ X,
    const u16* __restrict__ Wl, const u16* __restrict__ Wr,
    const float* __restrict__ bias, void* __restrict__ C0,
    void* __restrict__ C1, const int* __restrict__ batch,
    float* __restrict__ ssum, float* __restrict__ ssq, int K) {
  __shared__ u16 As[TM * TK];
  __shared__ u16 Ls[TM * TK];
  __shared__ u16 Xs[DUAL ? TM * TK : 1];
  __shared__ u16 Rs[DUAL ? TM * TK : 1];

  int id = blockIdx.x;
  const int nfull = (M_TILES >> 3) * 8 * JB;
  int m_t, j_t;
  if (id < nfull) {
    m_t = (id / (8 * JB)) * 8 + (id & 7);
    j_t = (id >> 3) & (JB - 1);
  } else {
    int rem = id - nfull;
    const int nrem = M_TILES & 7;  // 7
    m_t = (M_TILES & ~7) + rem % nrem;
    j_t = rem / nrem;
  }
  int m0 = m_t * TM;
  int j0 = j_t * 128;

  int tid = threadIdx.x;
  int lane = tid & 63;
  int wave = tid >> 6;
  int quad = lane >> 4;
  int lr = lane & 15;
  int wm = (wave & 1) * 64;
  int wn = (wave >> 1) * 64;

  f32x4 acc[4][4] = {};

  int sr = tid >> 2;
  int sc = (tid & 3) * 8;
  size_t moff0 = (size_t)(m0 + sr) * K + sc;
  size_t moff1 = moff0 + (size_t)64 * K;
  size_t joff0 = (size_t)(j0 + sr) * K + sc;
  size_t joff1 = joff0 + (size_t)64 * K;
  const int dofs = tid * 8;

  for (int k0 = 0; k0 < K; k0 += TK) {
    __syncthreads();
    gl_lds16(A + moff0 + k0, As + dofs);
    gl_lds16(A + moff1 + k0, As + 2048 + dofs);
    gl_lds16(Wl + joff0 + k0, Ls + dofs);
    gl_lds16(Wl + joff1 + k0, Ls + 2048 + dofs);
    if constexpr (DUAL) {
      gl_lds16(X + moff0 + k0, Xs + dofs);
      gl_lds16(X + moff1 + k0, Xs + 2048 + dofs);
      gl_lds16(Wr + joff0 + k0, Rs + dofs);
      gl_lds16(Wr + joff1 + k0, Rs + 2048 + dofs);
    }
    __syncthreads();
    {
      short8 af[4], lf[4];
#pragma unroll
      for (int t = 0; t < 4; ++t) {
        af[t] = *(const short8*)(As + (wm + t * 16 + lr) * TK + quad * 8);
        lf[t] = *(const short8*)(Ls + (wn + t * 16 + lr) * TK + quad * 8);
      }
#pragma unroll
      for (int ti = 0; ti < 4; ++ti)
#pragma unroll
        for (int tj = 0; tj < 4; ++tj)
          acc[ti][tj] = __builtin_amdgcn_mfma_f32_16x16x32_bf16(
              af[ti], lf[tj], acc[ti][tj], 0, 0, 0);
    }
    if constexpr (DUAL) {
      short8 xf[4], rf[4];
#pragma unroll
      for (int t = 0; t < 4; ++t) {
        xf[t] = *(const short8*)(Xs + (wm + t * 16 + lr) * TK + quad * 8);
        rf[t] = *(const short8*)(Rs + (wn + t * 16 + lr) * TK + quad * 8);
      }
#pragma unroll
      for (int ti = 0; ti < 4; ++ti)
#pragma unroll
        for (int tj = 0; tj < 4; ++tj)
          acc[ti][tj] = __builtin_amdgcn_mfma_f32_16x16x32_bf16(
              xf[ti], rf[tj], acc[ti][tj], 0, 0, 0);
    }
  }

  // epilogue: C/D layout col=lane&15, row=quad*4+reg (m89-verified)
  if constexpr (OUTMODE == 0) {
    int glo = batch[m0];
    int lastrow = m0 + TM - 1;
    bool fast = (lastrow < N_NODES) && (batch[lastrow] == glo);
#pragma unroll
    for (int tj = 0; tj < 4; ++tj) {
      int gcol = j0 + wn + tj * 16 + lr;
      float bv = bias[gcol];
      float s = 0.f, q = 0.f;
#pragma unroll
      for (int ti = 0; ti < 4; ++ti) {
        f32x4 v = acc[ti][tj];
        int rbase = m0 + wm + ti * 16 + quad * 4;
        if (fast) {
#pragma unroll
          for (int r = 0; r < 4; ++r) {
            float val = v[r] + bv;
            ((u16*)C0)[(size_t)(rbase + r) * H_DIM + gcol] = f2b(val);
            s += val; q += val * val;
          }
        } else {
          if (rbase + 3 < N_NODES && batch[rbase] == batch[rbase + 3]) {
            float s4 = 0.f, q4 = 0.f;
#pragma unroll
            for (int r = 0; r < 4; ++r) {
              float val = v[r] + bv;
              ((u16*)C0)[(size_t)(rbase + r) * H_DIM + gcol] = f2b(val);
              s4 += val; q4 += val * val;
            }
            int g = batch[rbase];
            atomicAdd(&ssum[g * H_DIM + gcol], s4);
            atomicAdd(&ssq[g * H_DIM + gcol], q4);
          } else {
#pragma unroll
            for (int r = 0; r < 4; ++r) {
              int grow = rbase + r;
              if (grow < N_NODES) {
                float val = v[r] + bv;
                ((u16*)C0)[(size_t)grow * H_DIM + gcol] = f2b(val);
                int g = batch[grow];
                atomicAdd(&ssum[g * H_DIM + gcol], val);
                atomicAdd(&ssq[g * H_DIM + gcol], val * val);
              }
            }
          }
        }
      }
      if (fast) {
        s += __shfl_xor(s, 16); s += __shfl_xor(s, 32);
        q += __shfl_xor(q, 16); q += __shfl_xor(q, 32);
        if (quad == 0) {
          atomicAdd(&ssum[glo * H_DIM + gcol], s);
          atomicAdd(&ssq[glo * H_DIM + gcol], q);
        }
      }
    }
  } else {
#pragma unroll
    for (int tj = 0; tj < 4; ++tj) {
      int gcol = j0 + wn + tj * 16 + lr;
#pragma unroll
      for (int ti = 0; ti < 4; ++ti) {
        f32x4 v = acc[ti][tj];
#pragma unroll
        for (int r = 0; r < 4; ++r) {
          int grow = m0 + wm + ti * 16 + quad * 4 + r;
          if (gcol < 128)
            ((u16*)C0)[(size_t)grow * 128 + gcol] = f2b(v[r]);
          else
            ((float*)C1)[(size_t)grow * 128 + (gcol - 128)] = v[r];
        }
      }
    }
  }
}

// ---------------- GraphNorm: precompute affine, then apply+relu -------------

__global__ void k_precomp(const float* __restrict__ ssum, const float* __restrict__ ssq,
                          const float* __restrict__ inv_sz, const float* __restrict__ gw,
                          const float* __restrict__ gb, const float* __restrict__ alpha,
                          float* __restrict__ S, float* __restrict__ T) {
  int idx = blockIdx.x * blockDim.x + threadIdx.x;
  if (idx >= N_GROUPS * H_DIM) return;
  int g = idx >> 9;
  int c = idx & (H_DIM - 1);
  float is = inv_sz[g];
  float m = ssum[idx] * is;
  float a = alpha[c];
  float var = fmaxf(ssq[idx] * is - a * (2.f - a) * m * m, 0.f);
  float inv = rsqrtf(var + EPSV);
  float sc = inv * gw[c];
  S[idx] = sc;
  T[idx] = gb[c] - a * m * sc;
}

__global__ void k_apply(u16* __restrict__ h, const int* __restrict__ batch,
                        const float* __restrict__ S, const float* __restrict__ T) {
  int tid = blockIdx.x * blockDim.x + threadIdx.x;
  if (tid >= N_NODES * (H_DIM / 8)) return;
  int n = tid >> 6;
  int c0 = (tid & 63) << 3;
  int g = batch[n];
  u16x8 hv = *(const u16x8*)(h + (size_t)n * H_DIM + c0);
  u16x8 out;
#pragma unroll
  for (int j = 0; j < 8; ++j) {
    int f = c0 + j;
    float y = b2f(hv[j]) * S[g * H_DIM + f] + T[g * H_DIM + f];
    out[j] = f2b(fmaxf(y, 0.f));
  }
  *(u16x8*)(h + (size_t)n * H_DIM + c0) = out;
}

// ---------------- driver ----------------

extern "C" void kernel_launch(void* const* d_in, const int* in_sizes, int n_in,
                              void* d_out, int out_size, void* d_ws, size_t ws_size,
                              hipStream_t stream) {
  const float* x = (const float*)d_in[0];
  const int* edge = (const int*)d_in[1];
  const int* batch = (const int*)d_in[2];
  const float *Wl[5], *Wr[5], *bb[5];
  for (int i = 0; i < 5; ++i) {
    Wl[i] = (const float*)d_in[3 + 3 * i];
    Wr[i] = (const float*)d_in[4 + 3 * i];
    bb[i] = (const float*)d_in[5 + 3 * i];
  }
  const float *gamma[4], *beta[4], *alpha[4];
  for (int i = 0; i < 4; ++i) {
    gamma[i] = (const float*)d_in[18 + 3 * i];
    beta[i]  = (const float*)d_in[19 + 3 * i];
    alpha[i] = (const float*)d_in[20 + 3 * i];
  }
  const int* srcv = edge;
  const int* dstv = edge + N_EDGES;

  char* base = (char*)d_ws;
  size_t off = 0;
  auto carve = [&](size_t bytes) -> char* {
    char* p = base + off;
    off = (off + bytes + 255) & ~(size_t)255;
    return p;
  };
  int* deg       = (int*)carve((size_t)N_NODES * 4);
  float* inv_deg = (float*)carve((size_t)N_NODES * 4);
  int* csr_off   = (int*)carve((size_t)(N_NODES + 1) * 4);
  int* cursor    = (int*)carve((size_t)N_NODES * 4);
  int* csr_src   = (int*)carve((size_t)N_EDGES * 4);
  int* bsum      = (int*)carve((size_t)SCAN_NBLK * 4);
  int* gstart    = (int*)carve((size_t)(N_GROUPS + 1) * 4);
  float* inv_sz  = (float*)carve((size_t)N_GROUPS * 4);
  float* stats   = (float*)carve((size_t)4 * 2 * N_GROUPS * H_DIM * 4);
  float* Sbuf    = (float*)carve((size_t)N_GROUPS * H_DIM * 4);
  float* Tbuf    = (float*)carve((size_t)N_GROUPS * H_DIM * 4);
  u16* xb        = (u16*)carve((size_t)XB_EL * 2);
  u16* aggx      = (u16*)carve((size_t)XB_EL * 2);
  u16* h0        = (u16*)carve((size_t)M_PAD * H_DIM * 2);
  u16* h1        = (u16*)carve((size_t)M_PAD * H_DIM * 2);
  u16* h2        = (u16*)carve((size_t)M_PAD * H_DIM * 2);
  u16* wall      = (u16*)carve((size_t)WALL_EL * 2);
  (void)ws_size; (void)in_sizes; (void)n_in; (void)out_size;

  u16* w1lb = wall;
  u16* w1rb = wall + 32768;
  u16* w2lb = wall + 65536;
  u16* w2rb = wall + 327680;
  u16* w3lb = wall + 589824;
  u16* w3rb = wall + 851968;
  u16* w4lb = wall + 1114112;
  u16* w4rb = wall + 1376256;
  u16* w5cat = wall + 1638400;  // 256 x 512

  // L5 P buffers alias h1 (dead at L5)
  u16* Plb = h1;
  float* Prf = (float*)((char*)h1 + (size_t)M_PAD * 128 * 2);

  // graph preprocessing
  hipMemsetAsync(deg, 0, (size_t)N_NODES * 4, stream);
  k_deg<<<(N_EDGES + 255) / 256, 256, 0, stream>>>(dstv, deg);
  k_scan1<<<SCAN_NBLK, SCAN_BLK, 0, stream>>>(deg, csr_off, bsum);
  k_scan2_gbounds<<<2, 256, 0, stream>>>(bsum, batch, gstart, inv_sz);
  k_scan3prep<<<SCAN_NBLK, SCAN_BLK, 0, stream>>>(csr_off, bsum, deg, inv_deg, cursor);
  k_scatter<<<(N_EDGES + 255) / 256, 256, 0, stream>>>(srcv, dstv, cursor, csr_src);
  hipMemsetAsync(stats, 0, (size_t)4 * 2 * N_GROUPS * H_DIM * 4, stream);

  WcSrc ws_src;
  ws_src.p[0] = Wl[0]; ws_src.p[1] = Wr[0];
  ws_src.p[2] = Wl[1]; ws_src.p[3] = Wr[1];
  ws_src.p[4] = Wl[2]; ws_src.p[5] = Wr[2];
  ws_src.p[6] = Wl[3]; ws_src.p[7] = Wr[3];
  ws_src.p[8] = Wl[4]; ws_src.p[9] = Wr[4];
  // convert (x->xb, W->wall) + layer-1 gather, one mixed dispatch
  k_conv_agg<<<CONV_BLKS + (N_NODES + 3) / 4, 256, 0, stream>>>(
      x, ws_src, xb, wall, csr_off, csr_src, inv_deg, aggx);

  const int nblk_main = M_TILES * 4;  // JB=4
  const int nblk_l5   = M_TILES * 2;  // JB=2
  dim3 aggblk(64, 8);
  int aggrid = (N_NODES + 3) / 4;

  auto stat_ptr = [&](int l) { return stats + (size_t)l * 2 * N_GROUPS * H_DIM; };
  auto norm = [&](u16* h, int l) {
    float* ss = stat_ptr(l);
    float* sq = ss + N_GROUPS * H_DIM;
    k_precomp<<<(N_GROUPS * H_DIM + 255) / 256, 256, 0, stream>>>(
        ss, sq, inv_sz, gamma[l], beta[l], alpha[l], Sbuf, Tbuf);
    k_apply<<<(N_NODES * (H_DIM / 8) + 255) / 256, 256, 0, stream>>>(
        h, batch, Sbuf, Tbuf);
  };

  // layer 1 (K = 64 padded)
  k_gemm_mfma<4, true, 0><<<nblk_main, 256, 0, stream>>>(
      aggx, xb, w1lb, w1rb, bb[0], h0, nullptr, batch,
      stat_ptr(0), stat_ptr(0) + N_GROUPS * H_DIM, K1PAD);
  norm(h0, 0);

  // layer 2
  k_agg512<<<aggrid, aggblk, 0, stream>>>(h0, csr_off, csr_src, inv_deg, h1);
  k_gemm_mfma<4, true, 0><<<nblk_main, 256, 0, stream>>>(
      h1, h0, w2lb, w2rb, bb[1], h2, nullptr, batch,
      stat_ptr(1), stat_ptr(1) + N_GROUPS * H_DIM, H_DIM);
  norm(h2, 1);

  // layer 3
  k_agg512<<<aggrid, aggblk, 0, stream>>>(h2, csr_off, csr_src, inv_deg, h0);
  k_gemm_mfma<4, true, 0><<<nblk_main, 256, 0, stream>>>(
      h0, h2, w3lb, w3rb, bb[2], h1, nullptr, batch,
      stat_ptr(2), stat_ptr(2) + N_GROUPS * H_DIM, H_DIM);
  norm(h1, 2);

  // layer 4
  k_agg512<<<aggrid, aggblk, 0, stream>>>(h1, csr_off, csr_src, inv_deg, h2);
  k_gemm_mfma<4, true, 0><<<nblk_main, 256, 0, stream>>>(
      h2, h1, w4lb, w4rb, bb[3], h0, nullptr, batch,
      stat_ptr(3), stat_ptr(3) + N_GROUPS * H_DIM, H_DIM);
  norm(h0, 3);

  // layer 5 via linearity: P = h0 @ [W5l|W5r]^T (J=256), then
  // out = inv_deg * segsum(Pl[src]) + Pr + b5
  k_gemm_mfma<2, false, 1><<<nblk_l5, 256, 0, stream>>>(
      h0, nullptr, w5cat, nullptr, nullptr, Plb, Prf, nullptr,
      nullptr, nullptr, H_DIM);
  k_agg_final<<<(N_NODES + 7) / 8, 256, 0, stream>>>(
      Plb, Prf, csr_off, csr_src, inv_deg, bb[4], (float*)d_out);
}